// Round 2
// baseline (32529.135 us; speedup 1.0000x reference)
//
#include <hip/hip_runtime.h>
#include <hip/hip_bf16.h>
#include <cstdint>

#define B_ 64
#define T_ 1024
#define I_ 128
#define R_ 2048
#define O_ 256
#define NBLK 128

typedef __attribute__((ext_vector_type(8))) __bf16 bf16x8;
typedef __attribute__((ext_vector_type(4))) float f32x4;
typedef unsigned short u16;
typedef unsigned int u32;

__device__ __forceinline__ u16 f2bf(float f) {
    u32 u = __builtin_bit_cast(u32, f);
    u32 r = (u + 0x7FFFu + ((u >> 16) & 1u)) >> 16;
    return (u16)r;
}

__device__ __forceinline__ bf16x8 ldbf8(const u16* p) {
    return *reinterpret_cast<const bf16x8*>(p);
}

// ---- prep kernels -------------------------------------------------------

__global__ void conv_bf16_kernel(const float* __restrict__ src,
                                 u16* __restrict__ dst, int n) {
    int stride = gridDim.x * blockDim.x;
    for (int i = blockIdx.x * blockDim.x + threadIdx.x; i < n; i += stride)
        dst[i] = f2bf(src[i]);
}

__global__ void bias_sum_kernel(const float* __restrict__ a,
                                const float* __restrict__ b,
                                float* __restrict__ c, int n) {
    int i = blockIdx.x * blockDim.x + threadIdx.x;
    if (i < n) c[i] = a[i] + b[i];
}

// in: [B][T][I] f32  ->  X: [T][B][I] bf16
__global__ void transpose_x_kernel(const float* __restrict__ in,
                                   u16* __restrict__ X) {
    const int total = T_ * B_ * I_;
    int stride = gridDim.x * blockDim.x;
    for (int idx = blockIdx.x * blockDim.x + threadIdx.x; idx < total; idx += stride) {
        int i  = idx & (I_ - 1);
        int tb = idx >> 7;          // I_=128
        int b  = tb & (B_ - 1);
        int t  = tb >> 6;           // B_=64
        X[idx] = f2bf(in[((size_t)b * T_ + t) * I_ + i]);
    }
}

// ---- persistent recurrent kernel ---------------------------------------
// 128 blocks x 256 threads (4 waves). Wave (bid, wid) owns the 16x16 output
// tile (m = bid>>5, n = (bid&31)*4 + wid) for ALL 1024 steps; its W_res
// B-fragments live in 256 VGPRs (64x bf16x8, statically indexed).
// One device-scope grid barrier per step; h double-buffered.
__global__ __launch_bounds__(256, 1) void esn_persistent(
    const u16* __restrict__ Wr, const u16* __restrict__ Wi,
    const u16* __restrict__ X, const float* __restrict__ bias,
    u16* __restrict__ hA, u16* __restrict__ hB,
    int* bar_cnt, int* bar_gen)
{
    const int lane = threadIdx.x & 63;
    const int wid  = threadIdx.x >> 6;
    const int bid  = blockIdx.x;
    const int mg   = bid >> 5;                 // 0..3
    const int n    = (bid & 31) * 4 + wid;     // 0..127
    const int row  = mg * 16 + (lane & 15);    // A-row this lane feeds
    const int col  = n * 16 + (lane & 15);     // B-col this lane feeds
    const int koff = (lane >> 4) * 8;

    // --- load weight fragments into registers (once) ---
    bf16x8 w[64];
    {
        const u16* Bh = Wr + (size_t)col * R_ + koff;
        #pragma unroll
        for (int kc = 0; kc < 64; ++kc) w[kc] = ldbf8(Bh + kc * 32);
    }
    bf16x8 wi[4];
    {
        const u16* Bx = Wi + (size_t)col * I_ + koff;
        #pragma unroll
        for (int kc = 0; kc < 4; ++kc) wi[kc] = ldbf8(Bx + kc * 32);
    }
    const float bs = bias[col];

    for (int t = 0; t < T_; ++t) {
        const u16* hin  = (t & 1) ? hB : hA;
        u16*       hout = (t & 1) ? hA : hB;

        f32x4 acc = {0.f, 0.f, 0.f, 0.f};

        // input projection (K=128)
        {
            const u16* Ax = X + ((size_t)t * B_ + row) * I_ + koff;
            #pragma unroll
            for (int kc = 0; kc < 4; ++kc)
                acc = __builtin_amdgcn_mfma_f32_16x16x32_bf16(ldbf8(Ax + kc * 32), wi[kc], acc, 0, 0, 0);
        }
        // recurrent part (K=2048), weights from registers
        {
            const u16* Ah = hin + (size_t)row * R_ + koff;
            #pragma unroll
            for (int kc = 0; kc < 64; ++kc)
                acc = __builtin_amdgcn_mfma_f32_16x16x32_bf16(ldbf8(Ah + kc * 32), w[kc], acc, 0, 0, 0);
        }

        // tanh + store (C/D layout: col = lane&15, row = (lane>>4)*4 + reg)
        #pragma unroll
        for (int i2 = 0; i2 < 4; ++i2) {
            int r = mg * 16 + (lane >> 4) * 4 + i2;
            hout[(size_t)r * R_ + col] = f2bf(tanhf(acc[i2] + bs));
        }

        // --- grid barrier (skip after last step; kernel boundary syncs) ---
        if (t != T_ - 1) {
            __threadfence();
            __syncthreads();
            if (threadIdx.x == 0) {
                const int g = t + 1;
                int old = __hip_atomic_fetch_add(bar_cnt, 1, __ATOMIC_ACQ_REL,
                                                 __HIP_MEMORY_SCOPE_AGENT);
                if (old == NBLK - 1) {
                    __hip_atomic_store(bar_cnt, 0, __ATOMIC_RELAXED,
                                       __HIP_MEMORY_SCOPE_AGENT);
                    __hip_atomic_store(bar_gen, g, __ATOMIC_RELEASE,
                                       __HIP_MEMORY_SCOPE_AGENT);
                } else {
                    while (__hip_atomic_load(bar_gen, __ATOMIC_ACQUIRE,
                                             __HIP_MEMORY_SCOPE_AGENT) < g) {
                        __builtin_amdgcn_s_sleep(2);
                    }
                }
            }
            __syncthreads();
        }
    }
}

// ---- readout ------------------------------------------------------------
__global__ __launch_bounds__(128) void readout_kernel(
    const u16* __restrict__ h, const u16* __restrict__ Wo,
    const float* __restrict__ b_out, float* __restrict__ out)
{
    const int lane = threadIdx.x & 63;
    const int wid  = threadIdx.x >> 6;
    const int g    = blockIdx.x * 2 + wid;   // 0..63
    const int m    = g >> 4;                 // 0..3
    const int n    = g & 15;                 // 0..15
    const int koff = (lane >> 4) * 8;
    const int b    = m * 16 + (lane & 15);
    const int col  = n * 16 + (lane & 15);

    f32x4 acc0 = {0.f,0.f,0.f,0.f};
    f32x4 acc1 = {0.f,0.f,0.f,0.f};
    f32x4 acc2 = {0.f,0.f,0.f,0.f};
    f32x4 acc3 = {0.f,0.f,0.f,0.f};

    const u16* Ah = h + (size_t)b * R_ + koff;
    const u16* Bh = Wo + (size_t)col * R_ + koff;
    #pragma unroll 4
    for (int kc = 0; kc < 64; kc += 4) {
        acc0 = __builtin_amdgcn_mfma_f32_16x16x32_bf16(ldbf8(Ah + (kc + 0) * 32), ldbf8(Bh + (kc + 0) * 32), acc0, 0, 0, 0);
        acc1 = __builtin_amdgcn_mfma_f32_16x16x32_bf16(ldbf8(Ah + (kc + 1) * 32), ldbf8(Bh + (kc + 1) * 32), acc1, 0, 0, 0);
        acc2 = __builtin_amdgcn_mfma_f32_16x16x32_bf16(ldbf8(Ah + (kc + 2) * 32), ldbf8(Bh + (kc + 2) * 32), acc2, 0, 0, 0);
        acc3 = __builtin_amdgcn_mfma_f32_16x16x32_bf16(ldbf8(Ah + (kc + 3) * 32), ldbf8(Bh + (kc + 3) * 32), acc3, 0, 0, 0);
    }

    f32x4 s = acc0 + acc1 + acc2 + acc3;
    const float bo = b_out[col];
    #pragma unroll
    for (int i2 = 0; i2 < 4; ++i2) {
        int row = m * 16 + (lane >> 4) * 4 + i2;
        out[(size_t)row * O_ + col] = s[i2] + bo;
    }
}

// ---- launch -------------------------------------------------------------

extern "C" void kernel_launch(void* const* d_in, const int* in_sizes, int n_in,
                              void* d_out, int out_size, void* d_ws, size_t ws_size,
                              hipStream_t stream) {
    const float* in    = (const float*)d_in[0];
    const float* Winw  = (const float*)d_in[1];
    const float* Winb  = (const float*)d_in[2];
    const float* Wresw = (const float*)d_in[3];
    const float* Wresb = (const float*)d_in[4];
    const float* Woutw = (const float*)d_in[5];
    const float* Woutb = (const float*)d_in[6];
    float* out = (float*)d_out;

    char* ws = (char*)d_ws;
    u16*   Wr   = (u16*)(ws);                      // 2048*2048*2 = 8388608
    u16*   Wi   = (u16*)(ws + 8388608);            // 2048*128*2  = 524288
    u16*   Wo   = (u16*)(ws + 8912896);            // 256*2048*2  = 1048576
    float* bias = (float*)(ws + 9961472);          // 2048*4      = 8192
    u16*   X    = (u16*)(ws + 9969664);            // 1024*64*128*2 = 16777216
    u16*   hA   = (u16*)(ws + 26746880);           // 64*2048*2   = 262144
    u16*   hB   = (u16*)(ws + 27009024);           // 64*2048*2   = 262144
    int*   bar  = (int*)(ws + 27271168);           // 2 ints
    // total: ~26 MB + 8B

    conv_bf16_kernel<<<2048, 256, 0, stream>>>(Wresw, Wr, R_ * R_);
    conv_bf16_kernel<<<256, 256, 0, stream>>>(Winw, Wi, R_ * I_);
    conv_bf16_kernel<<<512, 256, 0, stream>>>(Woutw, Wo, O_ * R_);
    bias_sum_kernel<<<8, 256, 0, stream>>>(Winb, Wresb, bias, R_);
    transpose_x_kernel<<<4096, 256, 0, stream>>>(in, X);
    hipMemsetAsync(hA, 0, (size_t)B_ * R_ * sizeof(u16), stream);
    hipMemsetAsync(bar, 0, 2 * sizeof(int), stream);

    esn_persistent<<<NBLK, 256, 0, stream>>>(Wr, Wi, X, bias, hA, hB,
                                             bar, bar + 1);

    // T_ = 1024 is even -> final h is in hA
    readout_kernel<<<32, 128, 0, stream>>>(hA, Wo, Woutb, out);
}

// Round 3
// 27739.630 us; speedup vs baseline: 1.1727x; 1.1727x over previous
//
#include <hip/hip_runtime.h>
#include <hip/hip_bf16.h>
#include <cstdint>

#define B_ 64
#define T_ 1024
#define I_ 128
#define R_ 2048
#define O_ 256
#define NBLK 256
#define NGRP 16

typedef __attribute__((ext_vector_type(8))) __bf16 bf16x8;
typedef __attribute__((ext_vector_type(4))) float f32x4;
typedef unsigned short u16;
typedef unsigned int u32;

__device__ __forceinline__ u16 f2bf(float f) {
    u32 u = __builtin_bit_cast(u32, f);
    u32 r = (u + 0x7FFFu + ((u >> 16) & 1u)) >> 16;
    return (u16)r;
}

__device__ __forceinline__ bf16x8 ldbf8(const u16* p) {
    return *reinterpret_cast<const bf16x8*>(p);
}

// convert 8 contiguous f32 -> bf16x8 (RNE)
__device__ __forceinline__ bf16x8 cvt8(const float* s) {
    union { u16 h[8]; bf16x8 v; } u;
    f32x4 a = *reinterpret_cast<const f32x4*>(s);
    f32x4 b = *reinterpret_cast<const f32x4*>(s + 4);
    u.h[0] = f2bf(a[0]); u.h[1] = f2bf(a[1]); u.h[2] = f2bf(a[2]); u.h[3] = f2bf(a[3]);
    u.h[4] = f2bf(b[0]); u.h[5] = f2bf(b[1]); u.h[6] = f2bf(b[2]); u.h[7] = f2bf(b[3]);
    return u.v;
}

// ---- prep kernels -------------------------------------------------------

__global__ void conv_bf16_kernel(const float* __restrict__ src,
                                 u16* __restrict__ dst, int n) {
    int stride = gridDim.x * blockDim.x;
    for (int i = blockIdx.x * blockDim.x + threadIdx.x; i < n; i += stride)
        dst[i] = f2bf(src[i]);
}

__global__ void bias_sum_kernel(const float* __restrict__ a,
                                const float* __restrict__ b,
                                float* __restrict__ c, int n) {
    int i = blockIdx.x * blockDim.x + threadIdx.x;
    if (i < n) c[i] = a[i] + b[i];
}

// ---- persistent recurrent kernel ---------------------------------------
// 256 blocks x 512 threads (8 waves). Block = (mh = bid>>7, nstrip = bid&127):
// computes rows mh*32..+32, cols nstrip*16..+16 every step. W_res strip
// (16 cols x 2048 K, bf16, XOR-swizzled) lives in LDS -- immune to the
// per-step L2 invalidation the agent-scope barrier requires.
// Waves: wid = kq*2 + msub; wave does K-quarter kq (512 wide) for m-subtile
// msub; partials reduced via LDS; waves 0/1 apply bias+tanh and store.
__global__ __launch_bounds__(512) void esn_persistent(
    const float* __restrict__ Wresw, const float* __restrict__ Winw,
    const float* __restrict__ input, const float* __restrict__ bias,
    u16* __restrict__ hA, u16* __restrict__ hB,
    int* __restrict__ cntg, int* __restrict__ cntr, int* __restrict__ flag)
{
    __shared__ u16 wr_lds[16 * R_];     // 64 KB, swizzled
    __shared__ u16 wi_lds[16 * I_];     // 4 KB, swizzled
    __shared__ f32x4 red[8][64];        // 8 KB

    const int tid  = threadIdx.x;
    const int lane = tid & 63;
    const int wid  = tid >> 6;
    const int bid  = blockIdx.x;
    const int mh   = bid >> 7;            // 0..1
    const int ns   = bid & 127;           // 0..127
    const int msub = wid & 1;             // 0..1
    const int kq   = wid >> 1;            // 0..3
    const int lcol = lane & 15;
    const int lkh  = lane >> 4;           // 0..3
    const int koff = lkh * 8;
    const int arow = mh * 32 + msub * 16 + lcol;   // batch row for A frags
    const int colg = ns * 16 + lcol;               // global output col
    const int swz  = (lcol & 7) << 4;

    // ---- stage W_res strip (f32 global -> bf16 LDS, swizzled), once ----
    #pragma unroll
    for (int it = 0; it < 8; ++it) {
        int idx = (it * 512 + tid) * 8;   // element in [16][2048] strip
        int c   = idx >> 11;
        int k   = idx & 2047;
        bf16x8 v = cvt8(Wresw + (size_t)(ns * 16 + c) * R_ + k);
        *reinterpret_cast<bf16x8*>((char*)&wr_lds[c * R_] + ((k * 2) ^ ((c & 7) << 4))) = v;
    }
    if (tid < 256) {
        int idx = tid * 8;                // element in [16][128] strip
        int c   = idx >> 7;
        int k   = idx & 127;
        bf16x8 v = cvt8(Winw + (size_t)(ns * 16 + c) * I_ + k);
        *reinterpret_cast<bf16x8*>((char*)&wi_lds[c * I_] + ((k * 2) ^ ((c & 7) << 4))) = v;
    }
    const float bs = bias[colg];
    __syncthreads();

    const char* bb = (const char*)wr_lds + lcol * (R_ * 2);

    for (int t = 0; t < T_; ++t) {
        const u16* hin  = (t & 1) ? hB : hA;
        u16*       hout = (t & 1) ? hA : hB;

        f32x4 acc = {0.f, 0.f, 0.f, 0.f};

        // input projection (K=128): only kq==0 waves, A converted on the fly
        if (kq == 0) {
            const float* Ax = input + ((size_t)arow * T_ + t) * I_ + koff;
            #pragma unroll
            for (int kc = 0; kc < 4; ++kc) {
                bf16x8 a = cvt8(Ax + kc * 32);
                bf16x8 b = *reinterpret_cast<const bf16x8*>(
                    (const char*)wi_lds + lcol * (I_ * 2) + ((kc * 64 + lkh * 16) ^ swz));
                acc = __builtin_amdgcn_mfma_f32_16x16x32_bf16(a, b, acc, 0, 0, 0);
            }
        }

        // recurrent part: this wave's K-quarter (512 wide)
        {
            const u16* Ah = hin + (size_t)arow * R_ + kq * 512 + koff;
            #pragma unroll
            for (int kc = 0; kc < 16; ++kc) {
                bf16x8 a = ldbf8(Ah + kc * 32);
                bf16x8 b = *reinterpret_cast<const bf16x8*>(
                    bb + ((kq * 1024 + kc * 64 + lkh * 16) ^ swz));
                acc = __builtin_amdgcn_mfma_f32_16x16x32_bf16(a, b, acc, 0, 0, 0);
            }
        }

        red[wid][lane] = acc;
        __syncthreads();

        // reduce K-quarters, tanh, store (waves 0/1: msub = wid)
        if (wid < 2) {
            f32x4 s = red[wid][lane];
            s += red[wid + 2][lane];
            s += red[wid + 4][lane];
            s += red[wid + 6][lane];
            #pragma unroll
            for (int i2 = 0; i2 < 4; ++i2) {
                int r = mh * 32 + wid * 16 + lkh * 4 + i2;
                hout[(size_t)r * R_ + colg] = f2bf(tanhf(s[i2] + bs));
            }
        }

        // ---- two-level grid barrier (one-shot per-step counters) ----
        if (t != T_ - 1) {
            __syncthreads();   // drains each wave's stores (vmcnt) before arrival
            if (tid == 0) {
                int grp = bid & (NGRP - 1);
                int old = __hip_atomic_fetch_add(&cntg[(t * NGRP + grp) * 32], 1,
                                                 __ATOMIC_ACQ_REL, __HIP_MEMORY_SCOPE_AGENT);
                if (old == (NBLK / NGRP) - 1) {
                    int ro = __hip_atomic_fetch_add(&cntr[t * 32], 1,
                                                    __ATOMIC_ACQ_REL, __HIP_MEMORY_SCOPE_AGENT);
                    if (ro == NGRP - 1)
                        __hip_atomic_store(&flag[t * 32], 1,
                                           __ATOMIC_RELEASE, __HIP_MEMORY_SCOPE_AGENT);
                }
                while (__hip_atomic_load(&flag[t * 32], __ATOMIC_ACQUIRE,
                                         __HIP_MEMORY_SCOPE_AGENT) == 0) {
                    __builtin_amdgcn_s_sleep(1);
                }
            }
            __syncthreads();
        }
    }
}

// ---- readout ------------------------------------------------------------
__global__ __launch_bounds__(128) void readout_kernel(
    const u16* __restrict__ h, const u16* __restrict__ Wo,
    const float* __restrict__ b_out, float* __restrict__ out)
{
    const int lane = threadIdx.x & 63;
    const int wid  = threadIdx.x >> 6;
    const int g    = blockIdx.x * 2 + wid;   // 0..63
    const int m    = g >> 4;
    const int n    = g & 15;
    const int koff = (lane >> 4) * 8;
    const int b    = m * 16 + (lane & 15);
    const int col  = n * 16 + (lane & 15);

    f32x4 acc0 = {0.f,0.f,0.f,0.f};
    f32x4 acc1 = {0.f,0.f,0.f,0.f};
    f32x4 acc2 = {0.f,0.f,0.f,0.f};
    f32x4 acc3 = {0.f,0.f,0.f,0.f};

    const u16* Ah = h + (size_t)b * R_ + koff;
    const u16* Bh = Wo + (size_t)col * R_ + koff;
    #pragma unroll 4
    for (int kc = 0; kc < 64; kc += 4) {
        acc0 = __builtin_amdgcn_mfma_f32_16x16x32_bf16(ldbf8(Ah + (kc + 0) * 32), ldbf8(Bh + (kc + 0) * 32), acc0, 0, 0, 0);
        acc1 = __builtin_amdgcn_mfma_f32_16x16x32_bf16(ldbf8(Ah + (kc + 1) * 32), ldbf8(Bh + (kc + 1) * 32), acc1, 0, 0, 0);
        acc2 = __builtin_amdgcn_mfma_f32_16x16x32_bf16(ldbf8(Ah + (kc + 2) * 32), ldbf8(Bh + (kc + 2) * 32), acc2, 0, 0, 0);
        acc3 = __builtin_amdgcn_mfma_f32_16x16x32_bf16(ldbf8(Ah + (kc + 3) * 32), ldbf8(Bh + (kc + 3) * 32), acc3, 0, 0, 0);
    }

    f32x4 s = acc0 + acc1 + acc2 + acc3;
    const float bo = b_out[col];
    #pragma unroll
    for (int i2 = 0; i2 < 4; ++i2) {
        int row = m * 16 + (lane >> 4) * 4 + i2;
        out[(size_t)row * O_ + col] = s[i2] + bo;
    }
}

// ---- launch -------------------------------------------------------------

extern "C" void kernel_launch(void* const* d_in, const int* in_sizes, int n_in,
                              void* d_out, int out_size, void* d_ws, size_t ws_size,
                              hipStream_t stream) {
    const float* in    = (const float*)d_in[0];
    const float* Winw  = (const float*)d_in[1];
    const float* Winb  = (const float*)d_in[2];
    const float* Wresw = (const float*)d_in[3];
    const float* Wresb = (const float*)d_in[4];
    const float* Woutw = (const float*)d_in[5];
    const float* Woutb = (const float*)d_in[6];
    float* out = (float*)d_out;

    char* ws = (char*)d_ws;
    u16*   Wo   = (u16*)(ws);                      // 256*2048*2 = 1048576
    float* bias = (float*)(ws + 1048576);          // 2048*4     = 8192
    u16*   hA   = (u16*)(ws + 1056768);            // 64*2048*2  = 262144
    u16*   hB   = (u16*)(ws + 1318912);            // 64*2048*2  = 262144
    int*   cntg = (int*)(ws + 1581056);            // 1024*16*128B = 2097152
    int*   cntr = (int*)(ws + 3678208);            // 1024*128B  = 131072
    int*   flag = (int*)(ws + 3809280);            // 1024*128B  = 131072
    // total: 3940352 bytes (~3.8 MB)

    conv_bf16_kernel<<<512, 256, 0, stream>>>(Woutw, Wo, O_ * R_);
    bias_sum_kernel<<<8, 256, 0, stream>>>(Winb, Wresb, bias, R_);
    hipMemsetAsync(hA, 0, (size_t)B_ * R_ * sizeof(u16), stream);
    hipMemsetAsync(cntg, 0, 2097152 + 131072 + 131072, stream);

    esn_persistent<<<NBLK, 512, 0, stream>>>(Wresw, Winw, in, bias,
                                             hA, hB, cntg, cntr, flag);

    // T_ = 1024 is even -> final h is in hA
    readout_kernel<<<32, 128, 0, stream>>>(hA, Wo, Woutb, out);
}

// Round 4
// 9501.528 us; speedup vs baseline: 3.4236x; 2.9195x over previous
//
#include <hip/hip_runtime.h>
#include <hip/hip_bf16.h>
#include <cstdint>

#define B_ 64
#define T_ 1024
#define I_ 128
#define R_ 2048
#define O_ 256
#define NBLK 256

typedef __attribute__((ext_vector_type(8))) __bf16 bf16x8;
typedef __attribute__((ext_vector_type(4))) float f32x4;
typedef unsigned short u16;
typedef unsigned int u32;
typedef unsigned long long u64;

#define AT_LD(p) __hip_atomic_load((p), __ATOMIC_RELAXED, __HIP_MEMORY_SCOPE_AGENT)
#define AT_ST(p, v) __hip_atomic_store((p), (v), __ATOMIC_RELAXED, __HIP_MEMORY_SCOPE_AGENT)

__device__ __forceinline__ u16 f2bf(float f) {
    u32 u = __builtin_bit_cast(u32, f);
    u32 r = (u + 0x7FFFu + ((u >> 16) & 1u)) >> 16;
    return (u16)r;
}

// convert 8 contiguous f32 -> bf16x8 (RNE)
__device__ __forceinline__ bf16x8 cvt8(const float* s) {
    union { u16 h[8]; bf16x8 v; } u;
    f32x4 a = *reinterpret_cast<const f32x4*>(s);
    f32x4 b = *reinterpret_cast<const f32x4*>(s + 4);
    u.h[0] = f2bf(a[0]); u.h[1] = f2bf(a[1]); u.h[2] = f2bf(a[2]); u.h[3] = f2bf(a[3]);
    u.h[4] = f2bf(b[0]); u.h[5] = f2bf(b[1]); u.h[6] = f2bf(b[2]); u.h[7] = f2bf(b[3]);
    return u.v;
}

__device__ __forceinline__ bf16x8 ldbf8(const u16* p) {
    return *reinterpret_cast<const bf16x8*>(p);
}

// ---- prep kernels -------------------------------------------------------

__global__ void conv_bf16_kernel(const float* __restrict__ src,
                                 u16* __restrict__ dst, int n) {
    int stride = gridDim.x * blockDim.x;
    for (int i = blockIdx.x * blockDim.x + threadIdx.x; i < n; i += stride)
        dst[i] = f2bf(src[i]);
}

__global__ void bias_sum_kernel(const float* __restrict__ a,
                                const float* __restrict__ b,
                                float* __restrict__ c, int n) {
    int i = blockIdx.x * blockDim.x + threadIdx.x;
    if (i < n) c[i] = a[i] + b[i];
}

// ---- persistent recurrent kernel ---------------------------------------
// 256 blocks x 512 threads. Block (rg = bid>>6, ns = bid&63) owns output
// rows rg*16..+16 x cols ns*32..+32 for all steps. Row-groups are CLOSED
// communication groups of 64 blocks (sync via 64 flag words, no RMW).
// All h stores/loads are agent-scope RELAXED atomics (sc1, IC-coherent,
// no fences -> no wbl2/inv cache thrash). W_res strip in swizzled LDS.
// Wave w (0..7) computes K-eighth w*256..+256 for BOTH 16-col halves.
__global__ __launch_bounds__(512, 1) void esn_persistent(
    const float* __restrict__ Wresw, const float* __restrict__ Winw,
    const float* __restrict__ input, const float* __restrict__ bias,
    u16* __restrict__ hA, u16* __restrict__ hB, u32* __restrict__ flags)
{
    __shared__ u16 wr_lds[32 * R_];     // 131072 B, XOR-swizzled
    __shared__ u16 wi_lds[32 * I_];     // 8192 B, XOR-swizzled
    __shared__ f32x4 red2[8][2][64];    // 16384 B
    __shared__ u16 out_lds[16 * 32];    // 1024 B

    const int tid  = threadIdx.x;
    const int lane = tid & 63;
    const int w    = tid >> 6;
    const int bid  = blockIdx.x;
    const int rg   = bid >> 6;          // row-group 0..3 (16 batch rows)
    const int ns   = bid & 63;          // col-strip 0..63 (32 cols)
    const int lcol = lane & 15;
    const int lkh  = lane >> 4;         // 0..3

    // ---- stage W_res strip (f32 -> bf16 LDS, swizzle byte^((col&15)<<4)) ----
    #pragma unroll
    for (int it = 0; it < 16; ++it) {
        int s  = it * 512 + tid;        // 16B slot 0..8191
        int c  = s >> 8;                // col 0..31
        int kb = (s & 255) * 16;        // byte offset in 4096B row
        bf16x8 v = cvt8(Wresw + (size_t)(ns * 32 + c) * R_ + kb / 2);
        *reinterpret_cast<bf16x8*>((char*)wr_lds + c * 4096 + (kb ^ ((c & 15) << 4))) = v;
    }
    {
        int c  = tid >> 4;              // col 0..31
        int kb = (tid & 15) * 16;       // byte offset in 256B row
        bf16x8 v = cvt8(Winw + (size_t)(ns * 32 + c) * I_ + kb / 2);
        *reinterpret_cast<bf16x8*>((char*)wi_lds + c * 256 + (kb ^ ((c & 15) << 4))) = v;
    }
    const float bs0 = bias[ns * 32 + lcol];
    const float bs1 = bias[ns * 32 + 16 + lcol];
    __syncthreads();

    u32* myflags = flags + rg * 64;
    const int swz = lcol << 4;

    for (int t = 0; t < T_; ++t) {
        const u16* hin  = (t & 1) ? hB : hA;
        u16*       hout = (t & 1) ? hA : hB;

        // ---- wait: all 64 blocks of my row-group published step t ----
        if (w == 0) {
            u32 f;
            do {
                f = AT_LD(&myflags[lane]);
            } while (!__all(f >= (u32)t));
        }
        __syncthreads();

        f32x4 acc0 = {0.f, 0.f, 0.f, 0.f};
        f32x4 acc1 = {0.f, 0.f, 0.f, 0.f};

        // ---- input projection chunk (waves 0..3 cover K_in=128) ----
        if (w < 4) {
            const float* Ax = input + ((size_t)(rg * 16 + lcol) * T_ + t) * I_ + w * 32 + lkh * 8;
            bf16x8 a = cvt8(Ax);
            int kb2 = (w * 32 + lkh * 8) * 2;
            bf16x8 b0 = *reinterpret_cast<const bf16x8*>(
                (const char*)wi_lds + lcol * 256 + (kb2 ^ swz));
            bf16x8 b1 = *reinterpret_cast<const bf16x8*>(
                (const char*)wi_lds + (16 + lcol) * 256 + (kb2 ^ swz));
            acc0 = __builtin_amdgcn_mfma_f32_16x16x32_bf16(a, b0, acc0, 0, 0, 0);
            acc1 = __builtin_amdgcn_mfma_f32_16x16x32_bf16(a, b1, acc1, 0, 0, 0);
        }

        // ---- recurrent: this wave's K-eighth (256 wide, 8 chunks) ----
        {
            const u16* Ah = hin + (size_t)(rg * 16 + lcol) * R_ + w * 256 + lkh * 8;
            // issue all 16 u64 IC loads first (static indexing)
            u64 q[16];
            #pragma unroll
            for (int j = 0; j < 8; ++j) {
                const u64* p = reinterpret_cast<const u64*>(Ah + j * 32);
                q[j * 2]     = AT_LD(p);
                q[j * 2 + 1] = AT_LD(p + 1);
            }
            #pragma unroll
            for (int j = 0; j < 8; ++j) {
                union { u64 qq[2]; bf16x8 v; } u;
                u.qq[0] = q[j * 2]; u.qq[1] = q[j * 2 + 1];
                int kb2 = (w * 256 + j * 32 + lkh * 8) * 2;
                bf16x8 b0 = *reinterpret_cast<const bf16x8*>(
                    (const char*)wr_lds + lcol * 4096 + (kb2 ^ swz));
                bf16x8 b1 = *reinterpret_cast<const bf16x8*>(
                    (const char*)wr_lds + (16 + lcol) * 4096 + (kb2 ^ swz));
                acc0 = __builtin_amdgcn_mfma_f32_16x16x32_bf16(u.v, b0, acc0, 0, 0, 0);
                acc1 = __builtin_amdgcn_mfma_f32_16x16x32_bf16(u.v, b1, acc1, 0, 0, 0);
            }
        }

        red2[w][0][lane] = acc0;
        red2[w][1][lane] = acc1;
        __syncthreads();

        // ---- wave 0: reduce K-eighths, tanh, store strip, publish ----
        if (w == 0) {
            #pragma unroll
            for (int nh = 0; nh < 2; ++nh) {
                f32x4 s = red2[0][nh][lane];
                #pragma unroll
                for (int ww = 1; ww < 8; ++ww) s += red2[ww][nh][lane];
                const float bs = nh ? bs1 : bs0;
                #pragma unroll
                for (int i2 = 0; i2 < 4; ++i2) {
                    float v = tanhf(s[i2] + bs);
                    // C/D layout: col = lane&15, row = (lane>>4)*4 + reg
                    out_lds[(lkh * 4 + i2) * 32 + nh * 16 + lcol] = f2bf(v);
                }
            }
            // gather 16B per lane (contiguous in h row-major), store via IC
            union { bf16x8 v; u64 qq[2]; } ov;
            ov.v = ldbf8(&out_lds[lane * 8]);   // [row=lane>>2][seg=(lane&3)*8]
            u16* dst = hout + (size_t)(rg * 16 + (lane >> 2)) * R_ + ns * 32 + (lane & 3) * 8;
            AT_ST(reinterpret_cast<u64*>(dst), ov.qq[0]);
            AT_ST(reinterpret_cast<u64*>(dst) + 1, ov.qq[1]);
            asm volatile("s_waitcnt vmcnt(0)" ::: "memory");
            __builtin_amdgcn_sched_barrier(0);
            if (lane == 0) AT_ST(&myflags[ns], (u32)(t + 1));
        }
    }
}

// ---- readout ------------------------------------------------------------
__global__ __launch_bounds__(128) void readout_kernel(
    const u16* __restrict__ h, const u16* __restrict__ Wo,
    const float* __restrict__ b_out, float* __restrict__ out)
{
    const int lane = threadIdx.x & 63;
    const int wid  = threadIdx.x >> 6;
    const int g    = blockIdx.x * 2 + wid;   // 0..63
    const int m    = g >> 4;
    const int n    = g & 15;
    const int koff = (lane >> 4) * 8;
    const int b    = m * 16 + (lane & 15);
    const int col  = n * 16 + (lane & 15);

    f32x4 acc0 = {0.f,0.f,0.f,0.f};
    f32x4 acc1 = {0.f,0.f,0.f,0.f};
    f32x4 acc2 = {0.f,0.f,0.f,0.f};
    f32x4 acc3 = {0.f,0.f,0.f,0.f};

    const u16* Ah = h + (size_t)b * R_ + koff;
    const u16* Bh = Wo + (size_t)col * R_ + koff;
    #pragma unroll 4
    for (int kc = 0; kc < 64; kc += 4) {
        acc0 = __builtin_amdgcn_mfma_f32_16x16x32_bf16(ldbf8(Ah + (kc + 0) * 32), ldbf8(Bh + (kc + 0) * 32), acc0, 0, 0, 0);
        acc1 = __builtin_amdgcn_mfma_f32_16x16x32_bf16(ldbf8(Ah + (kc + 1) * 32), ldbf8(Bh + (kc + 1) * 32), acc1, 0, 0, 0);
        acc2 = __builtin_amdgcn_mfma_f32_16x16x32_bf16(ldbf8(Ah + (kc + 2) * 32), ldbf8(Bh + (kc + 2) * 32), acc2, 0, 0, 0);
        acc3 = __builtin_amdgcn_mfma_f32_16x16x32_bf16(ldbf8(Ah + (kc + 3) * 32), ldbf8(Bh + (kc + 3) * 32), acc3, 0, 0, 0);
    }

    f32x4 s = acc0 + acc1 + acc2 + acc3;
    const float bo = b_out[col];
    #pragma unroll
    for (int i2 = 0; i2 < 4; ++i2) {
        int row = m * 16 + (lane >> 4) * 4 + i2;
        out[(size_t)row * O_ + col] = s[i2] + bo;
    }
}

// ---- launch -------------------------------------------------------------

extern "C" void kernel_launch(void* const* d_in, const int* in_sizes, int n_in,
                              void* d_out, int out_size, void* d_ws, size_t ws_size,
                              hipStream_t stream) {
    const float* in    = (const float*)d_in[0];
    const float* Winw  = (const float*)d_in[1];
    const float* Winb  = (const float*)d_in[2];
    const float* Wresw = (const float*)d_in[3];
    const float* Wresb = (const float*)d_in[4];
    const float* Woutw = (const float*)d_in[5];
    const float* Woutb = (const float*)d_in[6];
    float* out = (float*)d_out;

    char* ws = (char*)d_ws;
    u16*   Wo    = (u16*)(ws);                     // 256*2048*2 = 1048576
    float* bias  = (float*)(ws + 1048576);         // 2048*4     = 8192
    u16*   hA    = (u16*)(ws + 1056768);           // 64*2048*2  = 262144
    u16*   hB    = (u16*)(ws + 1318912);           // 64*2048*2  = 262144
    u32*   flags = (u32*)(ws + 1581056);           // 256*4      = 1024
    // total: ~1.6 MB

    conv_bf16_kernel<<<512, 256, 0, stream>>>(Woutw, Wo, O_ * R_);
    bias_sum_kernel<<<8, 256, 0, stream>>>(Winb, Wresb, bias, R_);
    hipMemsetAsync(hA, 0, (size_t)B_ * R_ * sizeof(u16), stream);
    hipMemsetAsync(flags, 0, NBLK * sizeof(u32), stream);

    esn_persistent<<<NBLK, 512, 0, stream>>>(Wresw, Winw, in, bias,
                                             hA, hB, flags);

    // T_ = 1024 even -> final h in hA
    readout_kernel<<<32, 128, 0, stream>>>(hA, Wo, Woutb, out);
}

// Round 5
// 6995.145 us; speedup vs baseline: 4.6502x; 1.3583x over previous
//
#include <hip/hip_runtime.h>
#include <hip/hip_bf16.h>
#include <cstdint>

#define B_ 64
#define T_ 1024
#define I_ 128
#define R_ 2048
#define O_ 256
#define NBLK 256

typedef __attribute__((ext_vector_type(8))) __bf16 bf16x8;
typedef __attribute__((ext_vector_type(4))) float f32x4;
typedef unsigned short u16;
typedef unsigned int u32;
typedef unsigned long long u64;

#define AT_LD(p) __hip_atomic_load((p), __ATOMIC_RELAXED, __HIP_MEMORY_SCOPE_AGENT)
#define AT_ST(p, v) __hip_atomic_store((p), (v), __ATOMIC_RELAXED, __HIP_MEMORY_SCOPE_AGENT)

__device__ __forceinline__ u16 f2bf(float f) {
    u32 u = __builtin_bit_cast(u32, f);
    u32 r = (u + 0x7FFFu + ((u >> 16) & 1u)) >> 16;
    return (u16)r;
}

// convert 8 f32 (two f32x4 regs) -> bf16x8 (RNE)
__device__ __forceinline__ bf16x8 cvt8r(f32x4 a, f32x4 b) {
    union { u16 h[8]; bf16x8 v; } u;
    u.h[0] = f2bf(a[0]); u.h[1] = f2bf(a[1]); u.h[2] = f2bf(a[2]); u.h[3] = f2bf(a[3]);
    u.h[4] = f2bf(b[0]); u.h[5] = f2bf(b[1]); u.h[6] = f2bf(b[2]); u.h[7] = f2bf(b[3]);
    return u.v;
}

__device__ __forceinline__ bf16x8 cvt8(const float* s) {
    return cvt8r(*reinterpret_cast<const f32x4*>(s),
                 *reinterpret_cast<const f32x4*>(s + 4));
}

__device__ __forceinline__ bf16x8 ldbf8(const u16* p) {
    return *reinterpret_cast<const bf16x8*>(p);
}

// ---- prep kernels -------------------------------------------------------

__global__ void conv_bf16_kernel(const float* __restrict__ src,
                                 u16* __restrict__ dst, int n) {
    int stride = gridDim.x * blockDim.x;
    for (int i = blockIdx.x * blockDim.x + threadIdx.x; i < n; i += stride)
        dst[i] = f2bf(src[i]);
}

__global__ void bias_sum_kernel(const float* __restrict__ a,
                                const float* __restrict__ b,
                                float* __restrict__ c, int n) {
    int i = blockIdx.x * blockDim.x + threadIdx.x;
    if (i < n) c[i] = a[i] + b[i];
}

// ---- persistent recurrent kernel ---------------------------------------
// 256 blocks x 512 threads, 1 block/CU (LDS-forced). Block (rg, ns) owns
// rows rg*16..+16 x cols ns*32..+32. Row-groups = closed groups of 64
// blocks, sync'd by 64 flag words (relaxed sc1, no RMW).
// Consumer protocol per step: relaxed poll -> ONE agent-acquire fence
// (single buffer_inv; L2 holds only clean lines since h stores are sc1
// write-through) -> plain CACHED h loads (L2 absorbs the 8-per-XCD reuse
// that round-4's sc1 loads pushed onto the IC every step).
__global__ __launch_bounds__(512, 1) void esn_persistent(
    const float* __restrict__ Wresw, const float* __restrict__ Winw,
    const float* __restrict__ input, const float* __restrict__ bias,
    u16* __restrict__ hA, u16* __restrict__ hB, u32* __restrict__ flags)
{
    __shared__ u16 wr_lds[32 * R_];     // 131072 B, XOR-swizzled
    __shared__ u16 wi_lds[32 * I_];     // 8192 B, XOR-swizzled
    __shared__ f32x4 red2[8][2][64];    // 16384 B
    __shared__ u16 out_lds[16 * 32];    // 1024 B

    const int tid  = threadIdx.x;
    const int lane = tid & 63;
    const int w    = tid >> 6;
    const int bid  = blockIdx.x;
    const int rg   = bid >> 6;          // row-group 0..3 (16 batch rows)
    const int ns   = bid & 63;          // col-strip 0..63 (32 cols)
    const int lcol = lane & 15;
    const int lkh  = lane >> 4;         // 0..3

    // ---- stage W_res strip (f32 -> bf16 LDS, swizzle byte^((col&15)<<4)) ----
    #pragma unroll
    for (int it = 0; it < 16; ++it) {
        int s  = it * 512 + tid;        // 16B slot 0..8191
        int c  = s >> 8;                // col 0..31
        int kb = (s & 255) * 16;        // byte offset in 4096B row
        bf16x8 v = cvt8(Wresw + (size_t)(ns * 32 + c) * R_ + kb / 2);
        *reinterpret_cast<bf16x8*>((char*)wr_lds + c * 4096 + (kb ^ ((c & 15) << 4))) = v;
    }
    {
        int c  = tid >> 4;              // col 0..31
        int kb = (tid & 15) * 16;       // byte offset in 256B row
        bf16x8 v = cvt8(Winw + (size_t)(ns * 32 + c) * I_ + kb / 2);
        *reinterpret_cast<bf16x8*>((char*)wi_lds + c * 256 + (kb ^ ((c & 15) << 4))) = v;
    }
    const float bs0 = bias[ns * 32 + lcol];
    const float bs1 = bias[ns * 32 + 16 + lcol];
    __syncthreads();

    u32* myflags = flags + rg * 64;
    const int swz = lcol << 4;

    for (int t = 0; t < T_; ++t) {
        const u16* hin  = (t & 1) ? hB : hA;
        u16*       hout = (t & 1) ? hA : hB;

        // ---- prefetch this step's input slice into regs (pre-fence) ----
        f32x4 xa, xb;
        if (w < 4) {
            const float* Ax = input + ((size_t)(rg * 16 + lcol) * T_ + t) * I_ + w * 32 + lkh * 8;
            xa = *reinterpret_cast<const f32x4*>(Ax);
            xb = *reinterpret_cast<const f32x4*>(Ax + 4);
        }

        // ---- wait: all 64 blocks of my row-group published step t ----
        if (w == 0) {
            u32 f;
            do {
                f = AT_LD(&myflags[lane]);
            } while (!__all(f >= (u32)t));
            // one cache-maintenance op per step: flash-inv clean L1/L2 so
            // plain cached loads below observe the IC-fresh h data
            __builtin_amdgcn_fence(__ATOMIC_ACQUIRE, "agent");
        }
        __syncthreads();

        f32x4 acc0 = {0.f, 0.f, 0.f, 0.f};
        f32x4 acc1 = {0.f, 0.f, 0.f, 0.f};

        // ---- input projection chunk (waves 0..3 cover K_in=128) ----
        if (w < 4) {
            bf16x8 a = cvt8r(xa, xb);
            int kb2 = (w * 32 + lkh * 8) * 2;
            bf16x8 b0 = *reinterpret_cast<const bf16x8*>(
                (const char*)wi_lds + lcol * 256 + (kb2 ^ swz));
            bf16x8 b1 = *reinterpret_cast<const bf16x8*>(
                (const char*)wi_lds + (16 + lcol) * 256 + (kb2 ^ swz));
            acc0 = __builtin_amdgcn_mfma_f32_16x16x32_bf16(a, b0, acc0, 0, 0, 0);
            acc1 = __builtin_amdgcn_mfma_f32_16x16x32_bf16(a, b1, acc1, 0, 0, 0);
        }

        // ---- recurrent: this wave's K-eighth (256 wide), PLAIN cached loads ----
        {
            const u16* Ah = hin + (size_t)(rg * 16 + lcol) * R_ + w * 256 + lkh * 8;
            bf16x8 hreg[8];
            #pragma unroll
            for (int j = 0; j < 8; ++j) hreg[j] = ldbf8(Ah + j * 32);
            #pragma unroll
            for (int j = 0; j < 8; ++j) {
                int kb2 = (w * 256 + j * 32 + lkh * 8) * 2;
                bf16x8 b0 = *reinterpret_cast<const bf16x8*>(
                    (const char*)wr_lds + lcol * 4096 + (kb2 ^ swz));
                bf16x8 b1 = *reinterpret_cast<const bf16x8*>(
                    (const char*)wr_lds + (16 + lcol) * 4096 + (kb2 ^ swz));
                acc0 = __builtin_amdgcn_mfma_f32_16x16x32_bf16(hreg[j], b0, acc0, 0, 0, 0);
                acc1 = __builtin_amdgcn_mfma_f32_16x16x32_bf16(hreg[j], b1, acc1, 0, 0, 0);
            }
        }

        red2[w][0][lane] = acc0;
        red2[w][1][lane] = acc1;
        __syncthreads();

        // ---- wave 0: reduce K-eighths, tanh, store strip, publish ----
        if (w == 0) {
            #pragma unroll
            for (int nh = 0; nh < 2; ++nh) {
                f32x4 s = red2[0][nh][lane];
                #pragma unroll
                for (int ww = 1; ww < 8; ++ww) s += red2[ww][nh][lane];
                const float bs = nh ? bs1 : bs0;
                #pragma unroll
                for (int i2 = 0; i2 < 4; ++i2) {
                    float v = tanhf(s[i2] + bs);
                    // C/D layout: col = lane&15, row = (lane>>4)*4 + reg
                    out_lds[(lkh * 4 + i2) * 32 + nh * 16 + lcol] = f2bf(v);
                }
            }
            // gather 16B per lane (contiguous in h row-major), sc1 write-through
            union { bf16x8 v; u64 qq[2]; } ov;
            ov.v = ldbf8(&out_lds[lane * 8]);   // [row=lane>>3][seg]
            u16* dst = hout + (size_t)(rg * 16 + (lane >> 2)) * R_ + ns * 32 + (lane & 3) * 8;
            AT_ST(reinterpret_cast<u64*>(dst), ov.qq[0]);
            AT_ST(reinterpret_cast<u64*>(dst) + 1, ov.qq[1]);
            asm volatile("s_waitcnt vmcnt(0)" ::: "memory");
            __builtin_amdgcn_sched_barrier(0);
            if (lane == 0) AT_ST(&myflags[ns], (u32)(t + 1));
        }
    }
}

// ---- readout ------------------------------------------------------------
__global__ __launch_bounds__(128) void readout_kernel(
    const u16* __restrict__ h, const u16* __restrict__ Wo,
    const float* __restrict__ b_out, float* __restrict__ out)
{
    const int lane = threadIdx.x & 63;
    const int wid  = threadIdx.x >> 6;
    const int g    = blockIdx.x * 2 + wid;   // 0..63
    const int m    = g >> 4;
    const int n    = g & 15;
    const int koff = (lane >> 4) * 8;
    const int b    = m * 16 + (lane & 15);
    const int col  = n * 16 + (lane & 15);

    f32x4 acc0 = {0.f,0.f,0.f,0.f};
    f32x4 acc1 = {0.f,0.f,0.f,0.f};
    f32x4 acc2 = {0.f,0.f,0.f,0.f};
    f32x4 acc3 = {0.f,0.f,0.f,0.f};

    const u16* Ah = h + (size_t)b * R_ + koff;
    const u16* Bh = Wo + (size_t)col * R_ + koff;
    #pragma unroll 4
    for (int kc = 0; kc < 64; kc += 4) {
        acc0 = __builtin_amdgcn_mfma_f32_16x16x32_bf16(ldbf8(Ah + (kc + 0) * 32), ldbf8(Bh + (kc + 0) * 32), acc0, 0, 0, 0);
        acc1 = __builtin_amdgcn_mfma_f32_16x16x32_bf16(ldbf8(Ah + (kc + 1) * 32), ldbf8(Bh + (kc + 1) * 32), acc1, 0, 0, 0);
        acc2 = __builtin_amdgcn_mfma_f32_16x16x32_bf16(ldbf8(Ah + (kc + 2) * 32), ldbf8(Bh + (kc + 2) * 32), acc2, 0, 0, 0);
        acc3 = __builtin_amdgcn_mfma_f32_16x16x32_bf16(ldbf8(Ah + (kc + 3) * 32), ldbf8(Bh + (kc + 3) * 32), acc3, 0, 0, 0);
    }

    f32x4 s = acc0 + acc1 + acc2 + acc3;
    const float bo = b_out[col];
    #pragma unroll
    for (int i2 = 0; i2 < 4; ++i2) {
        int row = m * 16 + (lane >> 4) * 4 + i2;
        out[(size_t)row * O_ + col] = s[i2] + bo;
    }
}

// ---- launch -------------------------------------------------------------

extern "C" void kernel_launch(void* const* d_in, const int* in_sizes, int n_in,
                              void* d_out, int out_size, void* d_ws, size_t ws_size,
                              hipStream_t stream) {
    const float* in    = (const float*)d_in[0];
    const float* Winw  = (const float*)d_in[1];
    const float* Winb  = (const float*)d_in[2];
    const float* Wresw = (const float*)d_in[3];
    const float* Wresb = (const float*)d_in[4];
    const float* Woutw = (const float*)d_in[5];
    const float* Woutb = (const float*)d_in[6];
    float* out = (float*)d_out;

    char* ws = (char*)d_ws;
    u16*   Wo    = (u16*)(ws);                     // 256*2048*2 = 1048576
    float* bias  = (float*)(ws + 1048576);         // 2048*4     = 8192
    u16*   hA    = (u16*)(ws + 1056768);           // 64*2048*2  = 262144
    u16*   hB    = (u16*)(ws + 1318912);           // 64*2048*2  = 262144
    u32*   flags = (u32*)(ws + 1581056);           // 256*4      = 1024
    // total: ~1.6 MB

    conv_bf16_kernel<<<512, 256, 0, stream>>>(Woutw, Wo, O_ * R_);
    bias_sum_kernel<<<8, 256, 0, stream>>>(Winb, Wresb, bias, R_);
    hipMemsetAsync(hA, 0, (size_t)B_ * R_ * sizeof(u16), stream);
    hipMemsetAsync(flags, 0, NBLK * sizeof(u32), stream);

    esn_persistent<<<NBLK, 512, 0, stream>>>(Wresw, Winw, in, bias,
                                             hA, hB, flags);

    // T_ = 1024 even -> final h in hA
    readout_kernel<<<32, 128, 0, stream>>>(hA, Wo, Woutb, out);
}

// Round 7
// 6818.670 us; speedup vs baseline: 4.7706x; 1.0259x over previous
//
#include <hip/hip_runtime.h>
#include <hip/hip_bf16.h>
#include <cstdint>

#define B_ 64
#define T_ 1024
#define I_ 128
#define R_ 2048
#define O_ 256
#define NBLK 256

typedef __attribute__((ext_vector_type(8))) __bf16 bf16x8;
typedef __attribute__((ext_vector_type(4))) float f32x4;
typedef unsigned short u16;
typedef unsigned int u32;
typedef unsigned long long u64;

#define AT_LD(p) __hip_atomic_load((p), __ATOMIC_RELAXED, __HIP_MEMORY_SCOPE_AGENT)
#define AT_ST(p, v) __hip_atomic_store((p), (v), __ATOMIC_RELAXED, __HIP_MEMORY_SCOPE_AGENT)

__device__ __forceinline__ u16 f2bf(float f) {
    u32 u = __builtin_bit_cast(u32, f);
    u32 r = (u + 0x7FFFu + ((u >> 16) & 1u)) >> 16;
    return (u16)r;
}

__device__ __forceinline__ bf16x8 cvt8r(f32x4 a, f32x4 b) {
    union { u16 h[8]; bf16x8 v; } u;
    u.h[0] = f2bf(a[0]); u.h[1] = f2bf(a[1]); u.h[2] = f2bf(a[2]); u.h[3] = f2bf(a[3]);
    u.h[4] = f2bf(b[0]); u.h[5] = f2bf(b[1]); u.h[6] = f2bf(b[2]); u.h[7] = f2bf(b[3]);
    return u.v;
}

__device__ __forceinline__ bf16x8 cvt8(const float* s) {
    return cvt8r(*reinterpret_cast<const f32x4*>(s),
                 *reinterpret_cast<const f32x4*>(s + 4));
}

__device__ __forceinline__ bf16x8 ldbf8(const u16* p) {
    return *reinterpret_cast<const bf16x8*>(p);
}

// ---- prep kernels -------------------------------------------------------

__global__ void conv_bf16_kernel(const float* __restrict__ src,
                                 u16* __restrict__ dst, int n) {
    int stride = gridDim.x * blockDim.x;
    for (int i = blockIdx.x * blockDim.x + threadIdx.x; i < n; i += stride)
        dst[i] = f2bf(src[i]);
}

__global__ void bias_sum_kernel(const float* __restrict__ a,
                                const float* __restrict__ b,
                                float* __restrict__ c, int n) {
    int i = blockIdx.x * blockDim.x + threadIdx.x;
    if (i < n) c[i] = a[i] + b[i];
}

// ---- persistent recurrent kernel ---------------------------------------
// Round-5 worker structure (proven correct/fast) with the per-block fence
// replaced by: (1) one elected delegate block per XCD does the single
// agent-acquire fence (buffer_inv: wipes that XCD L2 incl. any stale
// prefetched lines) after observing ALL 256 producer flags, publishing
// xcdflag[xcd]=t+1; (2) consumers gate on that one word and read h with
// L1-BYPASSING, L2-CACHED loads (global_load_dwordx4 ... sc0) so per-CU L1
// never needs invalidation. Producers unchanged: sc1 write-through +
// vmcnt(0) + relaxed flag.
__global__ __launch_bounds__(512, 1) void esn_persistent(
    const float* __restrict__ Wresw, const float* __restrict__ Winw,
    const float* __restrict__ input, const float* __restrict__ bias,
    u16* __restrict__ hA, u16* __restrict__ hB,
    u32* __restrict__ flags, u32* __restrict__ xcdflag, int* __restrict__ elect)
{
    __shared__ u16 wr_lds[32 * R_];     // 131072 B, XOR-swizzled
    __shared__ u16 wi_lds[32 * I_];     // 8192 B, XOR-swizzled
    __shared__ f32x4 red2[8][2][64];    // 16384 B
    __shared__ u16 out_lds[16 * 32];    // 1024 B
    __shared__ int s_xcd, s_isdel;

    const int tid  = threadIdx.x;
    const int lane = tid & 63;
    const int w    = tid >> 6;
    const int bid  = blockIdx.x;
    const int rg   = bid >> 6;          // row-group 0..3 (16 batch rows)
    const int ns   = bid & 63;          // col-strip 0..63 (32 cols)
    const int lcol = lane & 15;
    const int lkh  = lane >> 4;         // 0..3

    // ---- stage W_res strip (f32 -> bf16 LDS, swizzle byte^((col&15)<<4)) ----
    #pragma unroll
    for (int it = 0; it < 16; ++it) {
        int s  = it * 512 + tid;        // 16B slot 0..8191
        int c  = s >> 8;                // col 0..31
        int kb = (s & 255) * 16;        // byte offset in 4096B row
        bf16x8 v = cvt8(Wresw + (size_t)(ns * 32 + c) * R_ + kb / 2);
        *reinterpret_cast<bf16x8*>((char*)wr_lds + c * 4096 + (kb ^ ((c & 15) << 4))) = v;
    }
    {
        int c  = tid >> 4;              // col 0..31
        int kb = (tid & 15) * 16;       // byte offset in 256B row
        bf16x8 v = cvt8(Winw + (size_t)(ns * 32 + c) * I_ + kb / 2);
        *reinterpret_cast<bf16x8*>((char*)wi_lds + c * 256 + (kb ^ ((c & 15) << 4))) = v;
    }
    const float bs0 = bias[ns * 32 + lcol];
    const float bs1 = bias[ns * 32 + 16 + lcol];

    // ---- one-time per-XCD delegate election ----
    if (tid == 0) {
        u32 xcd;
        // HW_REG_XCC_ID = hwreg id 20 (gfx940+/gfx950, learn_hip m09)
        asm volatile("s_getreg_b32 %0, hwreg(20, 0, 32)" : "=s"(xcd));
        xcd &= 15;
        s_xcd = (int)xcd;
        int expected = -1;
        bool win = __hip_atomic_compare_exchange_strong(
            &elect[xcd], &expected, (int)bid,
            __ATOMIC_RELAXED, __ATOMIC_RELAXED, __HIP_MEMORY_SCOPE_AGENT);
        s_isdel = win ? 1 : 0;
    }
    __syncthreads();
    const int myxcd  = s_xcd;
    const int isdel  = s_isdel;
    const int swz = lcol << 4;

    for (int t = 0; t < T_; ++t) {
        const u16* hin  = (t & 1) ? hB : hA;
        u16*       hout = (t & 1) ? hA : hB;

        // ---- prefetch this step's input slice into regs (constant data) ----
        f32x4 xa, xb;
        if (w < 4) {
            const float* Ax = input + ((size_t)(rg * 16 + lcol) * T_ + t) * I_ + w * 32 + lkh * 8;
            xa = *reinterpret_cast<const f32x4*>(Ax);
            xb = *reinterpret_cast<const f32x4*>(Ax + 4);
        }

        // ---- gate: my XCD's L2 was invalidated after all step-t-1 stores ----
        if (w == 0) {
            while (AT_LD(&xcdflag[myxcd]) < (u32)t) { }
        }
        __syncthreads();

        f32x4 acc0 = {0.f, 0.f, 0.f, 0.f};
        f32x4 acc1 = {0.f, 0.f, 0.f, 0.f};

        // ---- input projection chunk (waves 0..3 cover K_in=128) ----
        if (w < 4) {
            bf16x8 a = cvt8r(xa, xb);
            int kb2 = (w * 32 + lkh * 8) * 2;
            bf16x8 b0 = *reinterpret_cast<const bf16x8*>(
                (const char*)wi_lds + lcol * 256 + (kb2 ^ swz));
            bf16x8 b1 = *reinterpret_cast<const bf16x8*>(
                (const char*)wi_lds + (16 + lcol) * 256 + (kb2 ^ swz));
            acc0 = __builtin_amdgcn_mfma_f32_16x16x32_bf16(a, b0, acc0, 0, 0, 0);
            acc1 = __builtin_amdgcn_mfma_f32_16x16x32_bf16(a, b1, acc1, 0, 0, 0);
        }

        // ---- recurrent: this wave's K-eighth; h via sc0 loads (L1-bypass,
        //      L2-cached) ----
        {
            const u16* Ah = hin + (size_t)(rg * 16 + lcol) * R_ + w * 256 + lkh * 8;
            bf16x8 h0, h1, h2, h3, h4, h5, h6, h7;
            asm volatile(
                "global_load_dwordx4 %0, %8, off sc0\n\t"
                "global_load_dwordx4 %1, %8, off offset:64 sc0\n\t"
                "global_load_dwordx4 %2, %8, off offset:128 sc0\n\t"
                "global_load_dwordx4 %3, %8, off offset:192 sc0\n\t"
                "global_load_dwordx4 %4, %8, off offset:256 sc0\n\t"
                "global_load_dwordx4 %5, %8, off offset:320 sc0\n\t"
                "global_load_dwordx4 %6, %8, off offset:384 sc0\n\t"
                "global_load_dwordx4 %7, %8, off offset:448 sc0\n\t"
                "s_waitcnt vmcnt(0)"
                : "=&v"(h0), "=&v"(h1), "=&v"(h2), "=&v"(h3),
                  "=&v"(h4), "=&v"(h5), "=&v"(h6), "=&v"(h7)
                : "v"(Ah)
                : "memory");

            #define RSTEP(J, HJ)                                                   \
            {                                                                      \
                int kb2 = (w * 256 + (J) * 32 + lkh * 8) * 2;                      \
                bf16x8 b0 = *reinterpret_cast<const bf16x8*>(                      \
                    (const char*)wr_lds + lcol * 4096 + (kb2 ^ swz));              \
                bf16x8 b1 = *reinterpret_cast<const bf16x8*>(                      \
                    (const char*)wr_lds + (16 + lcol) * 4096 + (kb2 ^ swz));       \
                acc0 = __builtin_amdgcn_mfma_f32_16x16x32_bf16(HJ, b0, acc0, 0, 0, 0); \
                acc1 = __builtin_amdgcn_mfma_f32_16x16x32_bf16(HJ, b1, acc1, 0, 0, 0); \
            }
            RSTEP(0, h0) RSTEP(1, h1) RSTEP(2, h2) RSTEP(3, h3)
            RSTEP(4, h4) RSTEP(5, h5) RSTEP(6, h6) RSTEP(7, h7)
            #undef RSTEP
        }

        red2[w][0][lane] = acc0;
        red2[w][1][lane] = acc1;
        __syncthreads();

        // ---- wave 0: reduce K-eighths, tanh, store strip, publish ----
        if (w == 0) {
            #pragma unroll
            for (int nh = 0; nh < 2; ++nh) {
                f32x4 s = red2[0][nh][lane];
                #pragma unroll
                for (int ww = 1; ww < 8; ++ww) s += red2[ww][nh][lane];
                const float bs = nh ? bs1 : bs0;
                #pragma unroll
                for (int i2 = 0; i2 < 4; ++i2) {
                    float v = tanhf(s[i2] + bs);
                    // C/D layout: col = lane&15, row = (lane>>4)*4 + reg
                    out_lds[(lkh * 4 + i2) * 32 + nh * 16 + lcol] = f2bf(v);
                }
            }
            // gather 16B per lane (contiguous in h row-major), sc1 write-through
            union { bf16x8 v; u64 qq[2]; } ov;
            ov.v = ldbf8(&out_lds[lane * 8]);   // [row=lane>>2][seg=(lane&3)*8]
            u16* dst = hout + (size_t)(rg * 16 + (lane >> 2)) * R_ + ns * 32 + (lane & 3) * 8;
            AT_ST(reinterpret_cast<u64*>(dst), ov.qq[0]);
            AT_ST(reinterpret_cast<u64*>(dst) + 1, ov.qq[1]);
            asm volatile("s_waitcnt vmcnt(0)" ::: "memory");
            __builtin_amdgcn_sched_barrier(0);
            if (lane == 0) AT_ST(&flags[rg * 64 + ns], (u32)(t + 1));

            // ---- delegate duty: after ALL producers publish t+1, invalidate
            //      this XCD's L2 (one buffer_inv) and open step t+1 ----
            if (isdel && t != T_ - 1) {
                const u32 tgt = (u32)(t + 1);
                u32 mn;
                do {
                    u32 a0 = AT_LD(&flags[lane * 4 + 0]);
                    u32 a1 = AT_LD(&flags[lane * 4 + 1]);
                    u32 a2 = AT_LD(&flags[lane * 4 + 2]);
                    u32 a3 = AT_LD(&flags[lane * 4 + 3]);
                    mn = min(min(a0, a1), min(a2, a3));
                } while (!__all((int)(mn >= tgt)));
                __builtin_amdgcn_fence(__ATOMIC_ACQUIRE, "agent");
                if (lane == 0) AT_ST(&xcdflag[myxcd], tgt);
            }
        }
    }
}

// ---- readout ------------------------------------------------------------
__global__ __launch_bounds__(128) void readout_kernel(
    const u16* __restrict__ h, const u16* __restrict__ Wo,
    const float* __restrict__ b_out, float* __restrict__ out)
{
    const int lane = threadIdx.x & 63;
    const int wid  = threadIdx.x >> 6;
    const int g    = blockIdx.x * 2 + wid;   // 0..63
    const int m    = g >> 4;
    const int n    = g & 15;
    const int koff = (lane >> 4) * 8;
    const int b    = m * 16 + (lane & 15);
    const int col  = n * 16 + (lane & 15);

    f32x4 acc0 = {0.f,0.f,0.f,0.f};
    f32x4 acc1 = {0.f,0.f,0.f,0.f};
    f32x4 acc2 = {0.f,0.f,0.f,0.f};
    f32x4 acc3 = {0.f,0.f,0.f,0.f};

    const u16* Ah = h + (size_t)b * R_ + koff;
    const u16* Bh = Wo + (size_t)col * R_ + koff;
    #pragma unroll 4
    for (int kc = 0; kc < 64; kc += 4) {
        acc0 = __builtin_amdgcn_mfma_f32_16x16x32_bf16(ldbf8(Ah + (kc + 0) * 32), ldbf8(Bh + (kc + 0) * 32), acc0, 0, 0, 0);
        acc1 = __builtin_amdgcn_mfma_f32_16x16x32_bf16(ldbf8(Ah + (kc + 1) * 32), ldbf8(Bh + (kc + 1) * 32), acc1, 0, 0, 0);
        acc2 = __builtin_amdgcn_mfma_f32_16x16x32_bf16(ldbf8(Ah + (kc + 2) * 32), ldbf8(Bh + (kc + 2) * 32), acc2, 0, 0, 0);
        acc3 = __builtin_amdgcn_mfma_f32_16x16x32_bf16(ldbf8(Ah + (kc + 3) * 32), ldbf8(Bh + (kc + 3) * 32), acc3, 0, 0, 0);
    }

    f32x4 s = acc0 + acc1 + acc2 + acc3;
    const float bo = b_out[col];
    #pragma unroll
    for (int i2 = 0; i2 < 4; ++i2) {
        int row = m * 16 + (lane >> 4) * 4 + i2;
        out[(size_t)row * O_ + col] = s[i2] + bo;
    }
}

// ---- launch -------------------------------------------------------------

extern "C" void kernel_launch(void* const* d_in, const int* in_sizes, int n_in,
                              void* d_out, int out_size, void* d_ws, size_t ws_size,
                              hipStream_t stream) {
    const float* in    = (const float*)d_in[0];
    const float* Winw  = (const float*)d_in[1];
    const float* Winb  = (const float*)d_in[2];
    const float* Wresw = (const float*)d_in[3];
    const float* Wresb = (const float*)d_in[4];
    const float* Woutw = (const float*)d_in[5];
    const float* Woutb = (const float*)d_in[6];
    float* out = (float*)d_out;

    char* ws = (char*)d_ws;
    u16*   Wo    = (u16*)(ws);                     // 256*2048*2 = 1048576
    float* bias  = (float*)(ws + 1048576);         // 2048*4     = 8192
    u16*   hA    = (u16*)(ws + 1056768);           // 64*2048*2  = 262144
    u16*   hB    = (u16*)(ws + 1318912);           // 64*2048*2  = 262144
    u32*   flags = (u32*)(ws + 1581056);           // 256*4      = 1024
    u32*   xcdfl = (u32*)(ws + 1582080);           // 16*4       = 64
    int*   elect = (int*)(ws + 1582144);           // 16*4       = 64
    // total: ~1.6 MB

    conv_bf16_kernel<<<512, 256, 0, stream>>>(Woutw, Wo, O_ * R_);
    bias_sum_kernel<<<8, 256, 0, stream>>>(Winb, Wresb, bias, R_);
    hipMemsetAsync(hA, 0, (size_t)B_ * R_ * sizeof(u16), stream);
    hipMemsetAsync(flags, 0, 256 * sizeof(u32), stream);
    hipMemsetAsync(xcdfl, 0, 16 * sizeof(u32), stream);
    hipMemsetAsync(elect, 0xFF, 16 * sizeof(int), stream);

    esn_persistent<<<NBLK, 512, 0, stream>>>(Wresw, Winw, in, bias,
                                             hA, hB, flags, xcdfl, elect);

    // T_ = 1024 even -> final h in hA
    readout_kernel<<<32, 128, 0, stream>>>(hA, Wo, Woutb, out);
}